// Round 1
// baseline (2846.546 us; speedup 1.0000x reference)
//
#include <hip/hip_runtime.h>
#include <hip/hip_bf16.h>

// Problem constants
// B=4, S=4096, D=512, FH=2048, H=64
// outputs: progress (B*S) ++ forecast (B*S) ++ fore (B*S*D), all f32

__device__ __forceinline__ float fsig(float x) {
    return 1.0f / (1.0f + __expf(-x));
}
__device__ __forceinline__ float ftanh(float x) {
    // tanh(x) = 1 - 2/(1+exp(2x)); stable at both extremes
    return 1.0f - 2.0f / (1.0f + __expf(2.0f * x));
}

// ---------------------------------------------------------------------------
// Generic tiled f32 GEMM: C[M][N] = A[M][K] @ op(B) + bias[N]
//   BT_LAYOUT=true : B given as Bt[N][K] (row-major, K inner)  -> C = A @ Bt^T
//   BT_LAYOUT=false: B given as B[K][N]  (row-major, N inner)  -> C = A @ B
// Requires M%64==0, N%64==0, K%16==0 (true for all uses here).
// ---------------------------------------------------------------------------
template<bool BT_LAYOUT>
__global__ __launch_bounds__(256) void gemm_f32_kernel(
    const float* __restrict__ A, const float* __restrict__ B,
    const float* __restrict__ bias, float* __restrict__ C,
    int M, int N, int K)
{
    constexpr int BM = 64, BN = 64, BK = 16;
    __shared__ float As[BK][BM + 4];
    __shared__ float Bs[BK][BN + 4];

    const int tid = threadIdx.x;
    const int bm = blockIdx.y * BM;
    const int bn = blockIdx.x * BN;
    const int tx = tid & 15;   // 0..15 -> col group
    const int ty = tid >> 4;   // 0..15 -> row group

    float acc[4][4] = {};

    for (int k0 = 0; k0 < K; k0 += BK) {
        // Load A tile (64 rows x 16 k): one float4 per thread, transpose to As[k][m]
        {
            const int r  = tid >> 2;        // 0..63
            const int cc = (tid & 3) * 4;   // 0,4,8,12
            const float4 av = *reinterpret_cast<const float4*>(
                &A[(size_t)(bm + r) * K + k0 + cc]);
            As[cc + 0][r] = av.x; As[cc + 1][r] = av.y;
            As[cc + 2][r] = av.z; As[cc + 3][r] = av.w;
        }
        if (BT_LAYOUT) {
            const int r  = tid >> 2;
            const int cc = (tid & 3) * 4;
            const float4 bv = *reinterpret_cast<const float4*>(
                &B[(size_t)(bn + r) * K + k0 + cc]);
            Bs[cc + 0][r] = bv.x; Bs[cc + 1][r] = bv.y;
            Bs[cc + 2][r] = bv.z; Bs[cc + 3][r] = bv.w;
        } else {
            const int r  = tid >> 4;        // k row 0..15
            const int cc = (tid & 15) * 4;  // 0..60
            const float4 bv = *reinterpret_cast<const float4*>(
                &B[(size_t)(k0 + r) * N + bn + cc]);
            Bs[r][cc + 0] = bv.x; Bs[r][cc + 1] = bv.y;
            Bs[r][cc + 2] = bv.z; Bs[r][cc + 3] = bv.w;
        }
        __syncthreads();

        #pragma unroll
        for (int k = 0; k < BK; ++k) {
            float a[4], b[4];
            #pragma unroll
            for (int i = 0; i < 4; ++i) a[i] = As[k][ty * 4 + i];
            #pragma unroll
            for (int j = 0; j < 4; ++j) b[j] = Bs[k][tx * 4 + j];
            #pragma unroll
            for (int i = 0; i < 4; ++i)
                #pragma unroll
                for (int j = 0; j < 4; ++j)
                    acc[i][j] = fmaf(a[i], b[j], acc[i][j]);
        }
        __syncthreads();
    }

    #pragma unroll
    for (int i = 0; i < 4; ++i) {
        const int row = bm + ty * 4 + i;
        #pragma unroll
        for (int j = 0; j < 4; ++j) {
            const int col = bn + tx * 4 + j;
            float v = acc[i][j];
            if (bias) v += bias[col];
            C[(size_t)row * N + col] = v;
        }
    }
}

// beff[i] = sum_k W2[i][k]*b1[k] + b2[i]   (512 outputs, K=2048)
__global__ __launch_bounds__(256) void beff_kernel(
    const float* __restrict__ W2, const float* __restrict__ b1,
    const float* __restrict__ b2, float* __restrict__ beff)
{
    const int i = blockIdx.x;        // 0..511
    const int tid = threadIdx.x;     // 0..255
    float s = 0.0f;
    for (int k = tid; k < 2048; k += 256)
        s = fmaf(W2[(size_t)i * 2048 + k], b1[k], s);
    #pragma unroll
    for (int off = 32; off; off >>= 1) s += __shfl_xor(s, off);
    __shared__ float red[4];
    if ((tid & 63) == 0) red[tid >> 6] = s;
    __syncthreads();
    if (tid == 0) beff[i] = red[0] + red[1] + red[2] + red[3] + b2[i];
}

// ---------------------------------------------------------------------------
// Sequential scan: one wave, 64 lanes = 64 hidden units.
// G[t][0:64]=i gates, [64:128]=f, [128:192]=g, [192:256]=o (pre-activation,
// missing bih+bhh+Whh*h which we add here).
// Stores c(t) per unit and p[t]=h(t) for the forecast pass.
// ---------------------------------------------------------------------------
__global__ __launch_bounds__(64) void scan_kernel(
    const float* __restrict__ G, const float* __restrict__ Whh,
    const float* __restrict__ bih, const float* __restrict__ bhh,
    const float* __restrict__ Whr,
    float* __restrict__ c_hist, float* __restrict__ p, int S)
{
    const int j = threadIdx.x; // lane 0..63
    const float w0 = Whh[j],        w1 = Whh[64 + j];
    const float w2 = Whh[128 + j],  w3 = Whh[192 + j];
    const float b0 = bih[j]       + bhh[j];
    const float b1_ = bih[64 + j] + bhh[64 + j];
    const float b2_ = bih[128 + j]+ bhh[128 + j];
    const float b3 = bih[192 + j] + bhh[192 + j];
    const float whr = Whr[j];

    float h = 0.0f, c = 0.0f;
    // software-pipelined gate loads
    float g0 = G[j], g1 = G[64 + j], g2 = G[128 + j], g3 = G[192 + j];

    for (int t = 0; t < S; ++t) {
        float n0 = 0.f, n1 = 0.f, n2 = 0.f, n3 = 0.f;
        if (t + 1 < S) {
            const float* Gn = G + (size_t)(t + 1) * 256;
            n0 = Gn[j]; n1 = Gn[64 + j]; n2 = Gn[128 + j]; n3 = Gn[192 + j];
        }
        const float gi = fmaf(w0, h, g0 + b0);
        const float gf = fmaf(w1, h, g1 + b1_);
        const float gg = fmaf(w2, h, g2 + b2_);
        const float go = fmaf(w3, h, g3 + b3);

        const float si = fsig(gi);
        const float sf = fsig(gf);
        const float tg = ftanh(gg);
        const float so = fsig(go);

        c = fmaf(sf, c, si * tg);
        c_hist[(size_t)t * 64 + j] = c;

        float hv = so * ftanh(c) * whr;
        hv += __shfl_xor(hv, 32);
        hv += __shfl_xor(hv, 16);
        hv += __shfl_xor(hv, 8);
        hv += __shfl_xor(hv, 4);
        hv += __shfl_xor(hv, 2);
        hv += __shfl_xor(hv, 1);
        h = hv;
        if (j == 0) p[t] = h;

        g0 = n0; g1 = n1; g2 = n2; g3 = n3;
    }
}

// ---------------------------------------------------------------------------
// Forecast cells: all t independent. 4 waves/block, one t per wave.
// ---------------------------------------------------------------------------
__global__ __launch_bounds__(256) void forecast_kernel(
    const float* __restrict__ Gf, const float* __restrict__ Whh,
    const float* __restrict__ bih, const float* __restrict__ bhh,
    const float* __restrict__ Whr, const float* __restrict__ c_hist,
    const float* __restrict__ p, float* __restrict__ pf, int S)
{
    const int wave = threadIdx.x >> 6;
    const int j = threadIdx.x & 63;
    const int t = blockIdx.x * 4 + wave;
    if (t >= S) return;

    const float h2 = p[t];
    const float c2 = c_hist[(size_t)t * 64 + j];
    const float* G = Gf + (size_t)t * 256;

    const float gi = G[j]        + bih[j]        + bhh[j]        + Whh[j] * h2;
    const float gf = G[64 + j]   + bih[64 + j]   + bhh[64 + j]   + Whh[64 + j] * h2;
    const float gg = G[128 + j]  + bih[128 + j]  + bhh[128 + j]  + Whh[128 + j] * h2;
    const float go = G[192 + j]  + bih[192 + j]  + bhh[192 + j]  + Whh[192 + j] * h2;

    const float cf = fsig(gf) * c2 + fsig(gi) * ftanh(gg);
    float hv = fsig(go) * ftanh(cf) * Whr[j];
    hv += __shfl_xor(hv, 32);
    hv += __shfl_xor(hv, 16);
    hv += __shfl_xor(hv, 8);
    hv += __shfl_xor(hv, 4);
    hv += __shfl_xor(hv, 2);
    hv += __shfl_xor(hv, 1);
    if (j == 0) pf[t] = hv;
}

// Broadcast p/pf to (B,S)
__global__ __launch_bounds__(256) void bcast_kernel(
    const float* __restrict__ p, const float* __restrict__ pf,
    float* __restrict__ out, int total, int Smask)
{
    const int i = blockIdx.x * blockDim.x + threadIdx.x;
    if (i < total) {
        out[i] = p[i & Smask];
        out[total + i] = pf[i & Smask];
    }
}

extern "C" void kernel_launch(void* const* d_in, const int* in_sizes, int n_in,
                              void* d_out, int out_size, void* d_ws, size_t ws_size,
                              hipStream_t stream) {
    const float* x   = (const float*)d_in[0];  // (4,4096,512)
    const float* W1  = (const float*)d_in[1];  // (2048,512)
    const float* b1  = (const float*)d_in[2];  // (2048)
    const float* W2  = (const float*)d_in[3];  // (512,2048)
    const float* b2  = (const float*)d_in[4];  // (512)
    const float* Wih = (const float*)d_in[5];  // (256,512)
    const float* Whh = (const float*)d_in[6];  // (256,1)
    const float* bih = (const float*)d_in[7];  // (256)
    const float* bhh = (const float*)d_in[8];  // (256)
    const float* Whr = (const float*)d_in[9];  // (1,64)
    float* out = (float*)d_out;

    constexpr int Bb = 4, S = 4096, D = 512, FH = 2048;
    const int M = Bb * S; // 16384

    // workspace layout (floats)
    float* ws     = (float*)d_ws;
    float* Weff   = ws;                       // 512*512
    float* beff   = Weff + 512 * 512;         // 512
    float* Gx     = beff + 512;               // 4096*256
    float* Gf     = Gx + S * 256;             // 4096*256
    float* c_hist = Gf + S * 256;             // 4096*64
    float* p      = c_hist + S * 64;          // 4096
    float* pf     = p + S;                    // 4096

    float* fore = out + 2 * M;                // (16384,512) region of d_out

    // 1) Weff = W2 @ W1  (A=W2[512][2048], B=W1[2048][512], B in [K][N] layout)
    gemm_f32_kernel<false><<<dim3(512 / 64, 512 / 64), 256, 0, stream>>>(
        W2, W1, nullptr, Weff, 512, 512, FH);

    // 2) beff = W2 @ b1 + b2
    beff_kernel<<<512, 256, 0, stream>>>(W2, b1, b2, beff);

    // 3) fore = flat @ Weff^T + beff
    gemm_f32_kernel<true><<<dim3(512 / 64, M / 64), 256, 0, stream>>>(
        x, Weff, beff, fore, M, 512, D);

    // 4) Gx = xs @ Wih^T   (xs = first 4096 rows of flat = x[0])
    gemm_f32_kernel<true><<<dim3(256 / 64, S / 64), 256, 0, stream>>>(
        x, Wih, nullptr, Gx, S, 256, D);

    // 5) sequential scan (single wave)
    scan_kernel<<<1, 64, 0, stream>>>(Gx, Whh, bih, bhh, Whr, c_hist, p, S);

    // 6) Gf = fs @ Wih^T   (fs = first 4096 rows of fore)
    gemm_f32_kernel<true><<<dim3(256 / 64, S / 64), 256, 0, stream>>>(
        fore, Wih, nullptr, Gf, S, 256, D);

    // 7) forecast cells (parallel over t)
    forecast_kernel<<<S / 4, 256, 0, stream>>>(
        Gf, Whh, bih, bhh, Whr, c_hist, p, pf, S);

    // 8) broadcast p/pf into outputs
    bcast_kernel<<<(Bb * S + 255) / 256, 256, 0, stream>>>(
        p, pf, out, Bb * S, S - 1);
}

// Round 2
// 914.132 us; speedup vs baseline: 3.1139x; 3.1139x over previous
//
#include <hip/hip_runtime.h>
#include <hip/hip_bf16.h>

// Problem constants
// B=4, S=4096, D=512, FH=2048, H=64
// outputs: progress (B*S) ++ forecast (B*S) ++ fore (B*S*D), all f32

#if __has_builtin(__builtin_amdgcn_exp2f)
__device__ __forceinline__ float EXP2(float x) { return __builtin_amdgcn_exp2f(x); }
#else
__device__ __forceinline__ float EXP2(float x) { return __expf(x * 0.6931471805599453f); }
#endif
#if __has_builtin(__builtin_amdgcn_rcpf)
__device__ __forceinline__ float RCPF(float x) { return __builtin_amdgcn_rcpf(x); }
#else
__device__ __forceinline__ float RCPF(float x) { return 1.0f / x; }
#endif

__device__ __forceinline__ float fsig(float x) {
    return 1.0f / (1.0f + __expf(-x));
}
__device__ __forceinline__ float ftanh(float x) {
    return 1.0f - 2.0f / (1.0f + __expf(2.0f * x));
}

// Wave64 sum via DPP: row_shr 1/2/4/8 then row_bcast15/31. Full sum lands in
// lane 63; other lanes hold partials. (LLVM atomic-optimizer sequence.)
__device__ __forceinline__ float dpp_sum64_lane63(float x) {
    x += __int_as_float(__builtin_amdgcn_update_dpp(0, __float_as_int(x), 0x111, 0xf, 0xf, true));
    x += __int_as_float(__builtin_amdgcn_update_dpp(0, __float_as_int(x), 0x112, 0xf, 0xf, true));
    x += __int_as_float(__builtin_amdgcn_update_dpp(0, __float_as_int(x), 0x114, 0xf, 0xf, true));
    x += __int_as_float(__builtin_amdgcn_update_dpp(0, __float_as_int(x), 0x118, 0xf, 0xf, true));
    x += __int_as_float(__builtin_amdgcn_update_dpp(0, __float_as_int(x), 0x142, 0xf, 0xf, true));
    x += __int_as_float(__builtin_amdgcn_update_dpp(0, __float_as_int(x), 0x143, 0xf, 0xf, true));
    return x;
}

// ---------------------------------------------------------------------------
// Generic tiled f32 GEMM: C[M][N] = A[M][K] @ op(B) + bias[N]
// ---------------------------------------------------------------------------
template<bool BT_LAYOUT>
__global__ __launch_bounds__(256) void gemm_f32_kernel(
    const float* __restrict__ A, const float* __restrict__ B,
    const float* __restrict__ bias, float* __restrict__ C,
    int M, int N, int K)
{
    constexpr int BM = 64, BN = 64, BK = 16;
    __shared__ float As[BK][BM + 4];
    __shared__ float Bs[BK][BN + 4];

    const int tid = threadIdx.x;
    const int bm = blockIdx.y * BM;
    const int bn = blockIdx.x * BN;
    const int tx = tid & 15;
    const int ty = tid >> 4;

    float acc[4][4] = {};

    for (int k0 = 0; k0 < K; k0 += BK) {
        {
            const int r  = tid >> 2;
            const int cc = (tid & 3) * 4;
            const float4 av = *reinterpret_cast<const float4*>(
                &A[(size_t)(bm + r) * K + k0 + cc]);
            As[cc + 0][r] = av.x; As[cc + 1][r] = av.y;
            As[cc + 2][r] = av.z; As[cc + 3][r] = av.w;
        }
        if (BT_LAYOUT) {
            const int r  = tid >> 2;
            const int cc = (tid & 3) * 4;
            const float4 bv = *reinterpret_cast<const float4*>(
                &B[(size_t)(bn + r) * K + k0 + cc]);
            Bs[cc + 0][r] = bv.x; Bs[cc + 1][r] = bv.y;
            Bs[cc + 2][r] = bv.z; Bs[cc + 3][r] = bv.w;
        } else {
            const int r  = tid >> 4;
            const int cc = (tid & 15) * 4;
            const float4 bv = *reinterpret_cast<const float4*>(
                &B[(size_t)(k0 + r) * N + bn + cc]);
            Bs[r][cc + 0] = bv.x; Bs[r][cc + 1] = bv.y;
            Bs[r][cc + 2] = bv.z; Bs[r][cc + 3] = bv.w;
        }
        __syncthreads();

        #pragma unroll
        for (int k = 0; k < BK; ++k) {
            float a[4], b[4];
            #pragma unroll
            for (int i = 0; i < 4; ++i) a[i] = As[k][ty * 4 + i];
            #pragma unroll
            for (int j = 0; j < 4; ++j) b[j] = Bs[k][tx * 4 + j];
            #pragma unroll
            for (int i = 0; i < 4; ++i)
                #pragma unroll
                for (int j = 0; j < 4; ++j)
                    acc[i][j] = fmaf(a[i], b[j], acc[i][j]);
        }
        __syncthreads();
    }

    #pragma unroll
    for (int i = 0; i < 4; ++i) {
        const int row = bm + ty * 4 + i;
        #pragma unroll
        for (int j = 0; j < 4; ++j) {
            const int col = bn + tx * 4 + j;
            float v = acc[i][j];
            if (bias) v += bias[col];
            C[(size_t)row * N + col] = v;
        }
    }
}

// beff[i] = sum_k W2[i][k]*b1[k] + b2[i]
__global__ __launch_bounds__(256) void beff_kernel(
    const float* __restrict__ W2, const float* __restrict__ b1,
    const float* __restrict__ b2, float* __restrict__ beff)
{
    const int i = blockIdx.x;
    const int tid = threadIdx.x;
    float s = 0.0f;
    for (int k = tid; k < 2048; k += 256)
        s = fmaf(W2[(size_t)i * 2048 + k], b1[k], s);
    #pragma unroll
    for (int off = 32; off; off >>= 1) s += __shfl_xor(s, off);
    __shared__ float red[4];
    if ((tid & 63) == 0) red[tid >> 6] = s;
    __syncthreads();
    if (tid == 0) beff[i] = red[0] + red[1] + red[2] + red[3] + b2[i];
}

// ---------------------------------------------------------------------------
// Sequential scan: one wave, 64 lanes = 64 hidden units.
// Critical-path optimized: exp2-folded gates, DPP reduction, depth-8 prefetch.
// ---------------------------------------------------------------------------
__global__ __launch_bounds__(64) void scan_kernel(
    const float* __restrict__ G, const float* __restrict__ Whh,
    const float* __restrict__ bih, const float* __restrict__ bhh,
    const float* __restrict__ Whr,
    float* __restrict__ c_hist, float* __restrict__ p, int S)
{
    constexpr float L2E  = 1.4426950408889634f;  // log2(e)
    constexpr float L2E2 = 2.8853900817779268f;  // 2*log2(e)
    const int j = threadIdx.x; // lane 0..63

    // sigmoid(x) = rcp(1 + exp2(-x*L2E)) -> fold -L2E into w,b
    // tanh(x)    = 1 - 2*rcp(1 + exp2(x*L2E2)) -> fold +L2E2 into w,b
    const float w0n = -Whh[j]       * L2E;
    const float w1n = -Whh[64 + j]  * L2E;
    const float w2s =  Whh[128 + j] * L2E2;
    const float w3n = -Whh[192 + j] * L2E;
    const float nb0 = -(bih[j]        + bhh[j])        * L2E;
    const float nb1 = -(bih[64 + j]   + bhh[64 + j])   * L2E;
    const float b2s =  (bih[128 + j]  + bhh[128 + j])  * L2E2;
    const float nb3 = -(bih[192 + j]  + bhh[192 + j])  * L2E;
    const float whr = Whr[j];

    float h = 0.0f, c = 0.0f;

    float g0_[8], g1_[8], g2_[8], g3_[8];
    #pragma unroll
    for (int s = 0; s < 8; ++s) {
        const float* Gs = G + (size_t)s * 256 + j;
        g0_[s] = Gs[0]; g1_[s] = Gs[64]; g2_[s] = Gs[128]; g3_[s] = Gs[192];
    }

#define LSTM_STEP(G0, G1, G2, G3, T)                                          \
    {                                                                         \
        const float pre0 = fmaf((G0), -L2E, nb0);                             \
        const float pre1 = fmaf((G1), -L2E, nb1);                             \
        const float pre2 = fmaf((G2),  L2E2, b2s);                            \
        const float pre3 = fmaf((G3), -L2E, nb3);                             \
        const float xi = fmaf(w0n, h, pre0);                                  \
        const float xf = fmaf(w1n, h, pre1);                                  \
        const float xg = fmaf(w2s, h, pre2);                                  \
        const float xo = fmaf(w3n, h, pre3);                                  \
        const float si = RCPF(1.0f + EXP2(xi));                               \
        const float sf = RCPF(1.0f + EXP2(xf));                               \
        const float tg = fmaf(-2.0f, RCPF(1.0f + EXP2(xg)), 1.0f);            \
        const float so = RCPF(1.0f + EXP2(xo));                               \
        c = fmaf(sf, c, si * tg);                                             \
        c_hist[(size_t)(T) * 64 + j] = c;                                     \
        const float tc = fmaf(-2.0f, RCPF(1.0f + EXP2(c * L2E2)), 1.0f);      \
        float hv = tc * (so * whr);                                           \
        hv = dpp_sum64_lane63(hv);                                            \
        h = __int_as_float(__builtin_amdgcn_readlane(__float_as_int(hv), 63));\
        if (j == 0) p[T] = h;                                                 \
    }

    int b = 0;
    for (; b < S - 8; b += 8) {
        #pragma unroll
        for (int s = 0; s < 8; ++s) {
            LSTM_STEP(g0_[s], g1_[s], g2_[s], g3_[s], b + s);
            const float* Gs = G + (size_t)(b + 8 + s) * 256 + j;
            g0_[s] = Gs[0]; g1_[s] = Gs[64]; g2_[s] = Gs[128]; g3_[s] = Gs[192];
        }
    }
    #pragma unroll
    for (int s = 0; s < 8; ++s)
        LSTM_STEP(g0_[s], g1_[s], g2_[s], g3_[s], b + s);
#undef LSTM_STEP
}

// ---------------------------------------------------------------------------
// Forecast cells: all t independent. 4 waves/block, one t per wave.
// ---------------------------------------------------------------------------
__global__ __launch_bounds__(256) void forecast_kernel(
    const float* __restrict__ Gf, const float* __restrict__ Whh,
    const float* __restrict__ bih, const float* __restrict__ bhh,
    const float* __restrict__ Whr, const float* __restrict__ c_hist,
    const float* __restrict__ p, float* __restrict__ pf, int S)
{
    const int wave = threadIdx.x >> 6;
    const int j = threadIdx.x & 63;
    const int t = blockIdx.x * 4 + wave;
    if (t >= S) return;

    const float h2 = p[t];
    const float c2 = c_hist[(size_t)t * 64 + j];
    const float* G = Gf + (size_t)t * 256;

    const float gi = G[j]        + bih[j]        + bhh[j]        + Whh[j] * h2;
    const float gf = G[64 + j]   + bih[64 + j]   + bhh[64 + j]   + Whh[64 + j] * h2;
    const float gg = G[128 + j]  + bih[128 + j]  + bhh[128 + j]  + Whh[128 + j] * h2;
    const float go = G[192 + j]  + bih[192 + j]  + bhh[192 + j]  + Whh[192 + j] * h2;

    const float cf = fsig(gf) * c2 + fsig(gi) * ftanh(gg);
    float hv = fsig(go) * ftanh(cf) * Whr[j];
    hv = dpp_sum64_lane63(hv);
    hv = __int_as_float(__builtin_amdgcn_readlane(__float_as_int(hv), 63));
    if (j == 0) pf[t] = hv;
}

// Broadcast p/pf to (B,S)
__global__ __launch_bounds__(256) void bcast_kernel(
    const float* __restrict__ p, const float* __restrict__ pf,
    float* __restrict__ out, int total, int Smask)
{
    const int i = blockIdx.x * blockDim.x + threadIdx.x;
    if (i < total) {
        out[i] = p[i & Smask];
        out[total + i] = pf[i & Smask];
    }
}

extern "C" void kernel_launch(void* const* d_in, const int* in_sizes, int n_in,
                              void* d_out, int out_size, void* d_ws, size_t ws_size,
                              hipStream_t stream) {
    const float* x   = (const float*)d_in[0];  // (4,4096,512)
    const float* W1  = (const float*)d_in[1];  // (2048,512)
    const float* b1  = (const float*)d_in[2];  // (2048)
    const float* W2  = (const float*)d_in[3];  // (512,2048)
    const float* b2  = (const float*)d_in[4];  // (512)
    const float* Wih = (const float*)d_in[5];  // (256,512)
    const float* Whh = (const float*)d_in[6];  // (256,1)
    const float* bih = (const float*)d_in[7];  // (256)
    const float* bhh = (const float*)d_in[8];  // (256)
    const float* Whr = (const float*)d_in[9];  // (1,64)
    float* out = (float*)d_out;

    constexpr int Bb = 4, S = 4096, D = 512, FH = 2048;
    const int M = Bb * S; // 16384

    // workspace layout (floats)
    float* ws     = (float*)d_ws;
    float* Weff   = ws;                       // 512*512
    float* beff   = Weff + 512 * 512;         // 512
    float* Gx     = beff + 512;               // 4096*256
    float* Gf     = Gx + S * 256;             // 4096*256
    float* c_hist = Gf + S * 256;             // 4096*64
    float* p      = c_hist + S * 64;          // 4096
    float* pf     = p + S;                    // 4096

    float* fore = out + 2 * M;                // (16384,512) region of d_out

    // 1) Weff = W2 @ W1
    gemm_f32_kernel<false><<<dim3(512 / 64, 512 / 64), 256, 0, stream>>>(
        W2, W1, nullptr, Weff, 512, 512, FH);

    // 2) beff = W2 @ b1 + b2
    beff_kernel<<<512, 256, 0, stream>>>(W2, b1, b2, beff);

    // 3) Gx = xs @ Wih^T  (put before the big GEMM so the scan's input is ready
    //    as early as possible)
    gemm_f32_kernel<true><<<dim3(256 / 64, S / 64), 256, 0, stream>>>(
        x, Wih, nullptr, Gx, S, 256, D);

    // 4) fore = flat @ Weff^T + beff
    gemm_f32_kernel<true><<<dim3(512 / 64, M / 64), 256, 0, stream>>>(
        x, Weff, beff, fore, M, 512, D);

    // 5) sequential scan (single wave)
    scan_kernel<<<1, 64, 0, stream>>>(Gx, Whh, bih, bhh, Whr, c_hist, p, S);

    // 6) Gf = fs @ Wih^T
    gemm_f32_kernel<true><<<dim3(256 / 64, S / 64), 256, 0, stream>>>(
        fore, Wih, nullptr, Gf, S, 256, D);

    // 7) forecast cells (parallel over t)
    forecast_kernel<<<S / 4, 256, 0, stream>>>(
        Gf, Whh, bih, bhh, Whr, c_hist, p, pf, S);

    // 8) broadcast p/pf into outputs
    bcast_kernel<<<(Bb * S + 255) / 256, 256, 0, stream>>>(
        p, pf, out, Bb * S, S - 1);
}